// Round 7
// baseline (43.847 us; speedup 1.0000x reference)
//
#include <hip/hip_runtime.h>
#include <cstdint>

namespace {

constexpr int NB = 320;   // batch
constexpr int ND = 128;   // feature dim
constexpr int NC = 80;    // label dim
constexpr int NANCH = 30;
constexpr int NW = 5;     // 64-bit words per 320-bit row

// ---- workspace layout (byte offsets) ----
constexpr size_t OFF_DIV  = 0;       // float[320]
constexpr size_t OFF_ASUM = 1280;    // double[320] (8-aligned)
constexpr size_t OFF_ACNT = 3840;    // int[320]

// K1: block a does EVERYTHING for row a: label packing (all rows, replicated
// per block -- cheap, L2-cached), fd row in LDS (never hits global), diversity,
// pos/neg classification, and the speculative per-anchor triplet sum/count.
// fd math is byte-identical to the absmax-0.0 lineage.
__global__ __launch_bounds__(256) void k_main(
    const int* __restrict__ label,
    const float* __restrict__ src,
    const float* __restrict__ tgt,
    float* __restrict__ divr,
    double* __restrict__ asum,
    int* __restrict__ acnt)
{
    const int a = blockIdx.x;
    const int tid = threadIdx.x;
    const int w = tid >> 6, lane = tid & 63;

    __shared__ float sa[ND];
    __shared__ float snsa;
    __shared__ float red[256];
    __shared__ unsigned long long pk[2 * NB];   // 5 KB: all packed label rows
    __shared__ float fdrow[NB];
    __shared__ unsigned long long pmask[NW], nmask[NW];
    __shared__ double wsum[4];

    if (tid < ND) sa[tid] = src[a * ND + tid];
    if (w == 0) {
        float s0 = src[a * ND + lane];
        float s1 = src[a * ND + lane + 64];
        float v = s0 * s0 + s1 * s1;
        for (int off = 32; off > 0; off >>= 1) v += __shfl_down(v, off);
        if (lane == 0) snsa = sqrtf(v);
    }
    // pack all 320 label rows; wave w handles rows w, w+4, ...
    for (int r = w; r < NB; r += 4) {
        int l0 = label[r * NC + lane];                              // c 0..63
        int l1 = (lane < NC - 64) ? label[r * NC + 64 + lane] : 0;  // c 64..79
        unsigned long long b0 = __ballot(l0 != 0);
        unsigned long long b1 = __ballot(l1 != 0);
        if (lane == 0) { pk[2 * r] = b0; pk[2 * r + 1] = b1; }
    }
    __syncthreads();

    // ---- fd row (identical order/ops to the validated k_fd) ----
    const float nsa = snsa;
    float acc = 0.f;
    for (int j = tid; j < NB; j += 256) {
        const float4* tp = reinterpret_cast<const float4*>(tgt + j * ND);
        float dot = 0.f, tn = 0.f;
#pragma unroll
        for (int d = 0; d < ND / 4; ++d) {
            float4 t = tp[d];
            dot += sa[4 * d + 0] * t.x + sa[4 * d + 1] * t.y +
                   sa[4 * d + 2] * t.z + sa[4 * d + 3] * t.w;
            tn += t.x * t.x + t.y * t.y + t.z * t.z + t.w * t.w;
        }
        float sim = dot / fmaxf(nsa * sqrtf(tn), 1e-8f);
        float f = fmaxf(1.0f - sim, 0.0f);
        fdrow[j] = f;
        acc += f;
    }
    red[tid] = acc;
    __syncthreads();
    for (int st = 128; st > 0; st >>= 1) {
        if (tid < st) red[tid] += red[tid + st];
        __syncthreads();
    }
    if (tid == 0) divr[a] = red[0] / (float)NB;

    // ---- classification of row a vs all j: one ballot per word ----
    const int pa = __popcll(pk[2 * a]) + __popcll(pk[2 * a + 1]);
    const float sna = sqrtf((float)pa);
#pragma unroll
    for (int it = 0; it < 2; ++it) {
        const int j = tid + 256 * it;        // round 1: wave 0 only (j 256..319)
        if (j < NB) {
            int pj = __popcll(pk[2 * j]) + __popcll(pk[2 * j + 1]);
            float denom = sna * sqrtf((float)pj);
            float dotf = (float)(__popcll(pk[2 * a] & pk[2 * j]) +
                                 __popcll(pk[2 * a + 1] & pk[2 * j + 1]));
            float ld = 1.0f - fminf(1.0f, dotf / denom);
            bool valid = (j != a) && (denom > 0.f);  // 0-label row -> NaN in ref -> excluded
            unsigned long long pb = __ballot(valid && (ld <= 0.2f));
            unsigned long long nb = __ballot(valid && (ld >= 0.5f));
            if (lane == 0) { pmask[j >> 6] = pb; nmask[j >> 6] = nb; }
        }
    }
    __syncthreads();

    // ---- speculative triplet sum for row a (pos/neg disjoint -> p != n) ----
    double s = 0.0;
#pragma unroll
    for (int it = 0; it < 2; ++it) {
        const int j = tid + 256 * it;
        if (j < NB && ((nmask[j >> 6] >> (j & 63)) & 1ull)) {
            const float fn = fdrow[j];
#pragma unroll
            for (int wd = 0; wd < NW; ++wd) {
                unsigned long long m = pmask[wd];
                while (m) {
                    const int b = __builtin_ctzll(m);
                    m &= m - 1;
                    float v = fdrow[wd * 64 + b] - fn + 0.5f;
                    if (v > 0.f) s += (double)v;
                }
            }
        }
    }
    for (int off = 32; off > 0; off >>= 1) s += __shfl_down(s, off);
    if (lane == 0) wsum[w] = s;
    __syncthreads();
    if (tid == 0) {
        int P = 0, N = 0;
#pragma unroll
        for (int wd = 0; wd < NW; ++wd) {
            P += __popcll(pmask[wd]);
            N += __popcll(nmask[wd]);
        }
        asum[a] = wsum[0] + wsum[1] + wsum[2] + wsum[3];
        acnt[a] = P * N;
    }
}

// K2: tiny tail -- rank-based top-30, gather 30 precomputed (sum, count), divide.
__global__ __launch_bounds__(320) void k_final(
    const float* __restrict__ divr,
    const double* __restrict__ asum,
    const int* __restrict__ acnt,
    float* __restrict__ out)
{
    const int tid = threadIdx.x;
    __shared__ float dv[NB];
    __shared__ int alist[NANCH];
    __shared__ double sl[NANCH];
    __shared__ int cl[NANCH];

    dv[tid] = divr[tid];
    __syncthreads();

    // rank = #{j: dv[j] > dv[tid] or (== and j < tid)}; ranks unique;
    // anchors are exactly ranks 0..29 (ties -> lowest index, = lax.top_k)
    const float ve = dv[tid];
    int rank = 0;
#pragma unroll 8
    for (int j = 0; j < NB; ++j) {
        float vj = dv[j];
        rank += (vj > ve) || (vj == ve && j < tid);
    }
    if (rank < NANCH) alist[rank] = tid;
    __syncthreads();

    if (tid < NANCH) {
        sl[tid] = asum[alist[tid]];
        cl[tid] = acnt[alist[tid]];
    }
    __syncthreads();
    if (tid == 0) {
        double S = 0.0;
        long long C = 0;
        for (int r = 0; r < NANCH; ++r) { S += sl[r]; C += cl[r]; }
        out[0] = (float)(S / ((double)C + 1e-4));
    }
}

} // namespace

extern "C" void kernel_launch(void* const* d_in, const int* in_sizes, int n_in,
                              void* d_out, int out_size, void* d_ws, size_t ws_size,
                              hipStream_t stream) {
    const int* label = (const int*)d_in[0];
    const float* src = (const float*)d_in[1];
    const float* tgt = (const float*)d_in[2];

    char* ws = (char*)d_ws;
    float* divr  = (float*)(ws + OFF_DIV);
    double* asum = (double*)(ws + OFF_ASUM);
    int* acnt    = (int*)(ws + OFF_ACNT);

    k_main <<<NB, 256, 0, stream>>>(label, src, tgt, divr, asum, acnt);
    k_final<<<1, 320, 0, stream>>>(divr, asum, acnt, (float*)d_out);
}

// Round 8
// 32.625 us; speedup vs baseline: 1.3440x; 1.3440x over previous
//
#include <hip/hip_runtime.h>
#include <cstdint>

namespace {

constexpr int NB = 320;   // batch
constexpr int ND = 128;   // feature dim
constexpr int NC = 80;    // label dim
constexpr int NANCH = 30;
constexpr int NW = 5;     // 64-bit words per 320-bit row

// ---- workspace layout (byte offsets) ----
constexpr size_t OFF_DIV  = 0;       // float[320]
constexpr size_t OFF_ASUM = 1280;    // double[320] (8-aligned)
constexpr size_t OFF_ACNT = 3840;    // int[320]

// K1: block a does everything for row a. Label-side work is per-thread
// register packing from raw labels (independent int4 loads, no cross-lane
// chains) -- row a's own mask is packed once by wave 1 (2 ballots).
// fd math is byte-identical to the absmax-0.0 lineage.
__global__ __launch_bounds__(256) void k_main(
    const int* __restrict__ label,
    const float* __restrict__ src,
    const float* __restrict__ tgt,
    float* __restrict__ divr,
    double* __restrict__ asum,
    int* __restrict__ acnt)
{
    const int a = blockIdx.x;
    const int tid = threadIdx.x;
    const int w = tid >> 6, lane = tid & 63;

    __shared__ float sa[ND];
    __shared__ float snsa;
    __shared__ float red[256];
    __shared__ float fdrow[NB];
    __shared__ unsigned long long am[2];        // row a's packed labels
    __shared__ unsigned long long pmask[NW], nmask[NW];
    __shared__ double wsum[4];

    if (tid < ND) sa[tid] = src[a * ND + tid];
    if (w == 0) {
        float s0 = src[a * ND + lane];
        float s1 = src[a * ND + lane + 64];
        float v = s0 * s0 + s1 * s1;
        for (int off = 32; off > 0; off >>= 1) v += __shfl_down(v, off);
        if (lane == 0) snsa = sqrtf(v);
    } else if (w == 1) {
        int l0 = label[a * NC + lane];                              // c 0..63
        int l1 = (lane < NC - 64) ? label[a * NC + 64 + lane] : 0;  // c 64..79
        unsigned long long b0 = __ballot(l0 != 0);
        unsigned long long b1 = __ballot(l1 != 0);
        if (lane == 0) { am[0] = b0; am[1] = b1; }
    }
    __syncthreads();

    // ---- fd row (identical order/ops to the validated k_fd) ----
    const float nsa = snsa;
    float acc = 0.f;
    for (int j = tid; j < NB; j += 256) {
        const float4* tp = reinterpret_cast<const float4*>(tgt + j * ND);
        float dot = 0.f, tn = 0.f;
#pragma unroll
        for (int d = 0; d < ND / 4; ++d) {
            float4 t = tp[d];
            dot += sa[4 * d + 0] * t.x + sa[4 * d + 1] * t.y +
                   sa[4 * d + 2] * t.z + sa[4 * d + 3] * t.w;
            tn += t.x * t.x + t.y * t.y + t.z * t.z + t.w * t.w;
        }
        float sim = dot / fmaxf(nsa * sqrtf(tn), 1e-8f);
        float f = fmaxf(1.0f - sim, 0.0f);
        fdrow[j] = f;
        acc += f;
    }
    red[tid] = acc;
    __syncthreads();
    for (int st = 128; st > 0; st >>= 1) {
        if (tid < st) red[tid] += red[tid + st];
        __syncthreads();
    }
    if (tid == 0) divr[a] = red[0] / (float)NB;

    // ---- classification: per-thread register packing of row j ----
    const unsigned long long a0 = am[0], a1 = am[1];
    const float sna = sqrtf((float)(__popcll(a0) + __popcll(a1)));
#pragma unroll
    for (int it = 0; it < 2; ++it) {
        const int j = tid + 256 * it;              // wave-uniform guard below
        if (j < NB) {
            const int4* lp = reinterpret_cast<const int4*>(label + j * NC);
            unsigned long long j0 = 0, j1 = 0;
#pragma unroll
            for (int q = 0; q < 16; ++q) {         // c = 0..63
                int4 v = lp[q];
                j0 |= (unsigned long long)(v.x != 0) << (4 * q + 0);
                j0 |= (unsigned long long)(v.y != 0) << (4 * q + 1);
                j0 |= (unsigned long long)(v.z != 0) << (4 * q + 2);
                j0 |= (unsigned long long)(v.w != 0) << (4 * q + 3);
            }
#pragma unroll
            for (int q = 16; q < 20; ++q) {        // c = 64..79
                int4 v = lp[q];
                const int b = 4 * (q - 16);
                j1 |= (unsigned long long)(v.x != 0) << (b + 0);
                j1 |= (unsigned long long)(v.y != 0) << (b + 1);
                j1 |= (unsigned long long)(v.z != 0) << (b + 2);
                j1 |= (unsigned long long)(v.w != 0) << (b + 3);
            }
            const float snj = sqrtf((float)(__popcll(j0) + __popcll(j1)));
            const float denom = sna * snj;
            const float dotf = (float)(__popcll(a0 & j0) + __popcll(a1 & j1));
            const float ld = 1.0f - fminf(1.0f, dotf / denom);
            const bool valid = (j != a) && (denom > 0.f); // 0-label -> NaN in ref -> excluded
            unsigned long long pb = __ballot(valid && (ld <= 0.2f));
            unsigned long long nb = __ballot(valid && (ld >= 0.5f));
            if (lane == 0) { pmask[j >> 6] = pb; nmask[j >> 6] = nb; }
        }
    }
    __syncthreads();

    // ---- speculative triplet sum for row a (pos/neg disjoint -> p != n) ----
    double s = 0.0;
#pragma unroll
    for (int it = 0; it < 2; ++it) {
        const int j = tid + 256 * it;
        if (j < NB && ((nmask[j >> 6] >> (j & 63)) & 1ull)) {
            const float fn = fdrow[j];
#pragma unroll
            for (int wd = 0; wd < NW; ++wd) {
                unsigned long long m = pmask[wd];
                while (m) {
                    const int b = __builtin_ctzll(m);
                    m &= m - 1;
                    float v = fdrow[wd * 64 + b] - fn + 0.5f;
                    if (v > 0.f) s += (double)v;
                }
            }
        }
    }
    for (int off = 32; off > 0; off >>= 1) s += __shfl_down(s, off);
    if (lane == 0) wsum[w] = s;
    __syncthreads();
    if (tid == 0) {
        int P = 0, N = 0;
#pragma unroll
        for (int wd = 0; wd < NW; ++wd) {
            P += __popcll(pmask[wd]);
            N += __popcll(nmask[wd]);
        }
        asum[a] = wsum[0] + wsum[1] + wsum[2] + wsum[3];
        acnt[a] = P * N;
    }
}

// K2: tiny tail -- rank-based top-30, gather precomputed (sum, count), divide.
__global__ __launch_bounds__(320) void k_final(
    const float* __restrict__ divr,
    const double* __restrict__ asum,
    const int* __restrict__ acnt,
    float* __restrict__ out)
{
    const int tid = threadIdx.x;
    __shared__ float dv[NB];
    __shared__ int alist[NANCH];
    __shared__ double sl[NANCH];
    __shared__ int cl[NANCH];

    dv[tid] = divr[tid];
    __syncthreads();

    // rank = #{j: dv[j] > dv[tid] or (== and j < tid)}; ranks unique;
    // anchors are exactly ranks 0..29 (ties -> lowest index, = lax.top_k)
    const float ve = dv[tid];
    int rank = 0;
#pragma unroll 8
    for (int j = 0; j < NB; ++j) {
        float vj = dv[j];
        rank += (vj > ve) || (vj == ve && j < tid);
    }
    if (rank < NANCH) alist[rank] = tid;
    __syncthreads();

    if (tid < NANCH) {
        sl[tid] = asum[alist[tid]];
        cl[tid] = acnt[alist[tid]];
    }
    __syncthreads();
    if (tid == 0) {
        double S = 0.0;
        long long C = 0;
        for (int r = 0; r < NANCH; ++r) { S += sl[r]; C += cl[r]; }
        out[0] = (float)(S / ((double)C + 1e-4));
    }
}

} // namespace

extern "C" void kernel_launch(void* const* d_in, const int* in_sizes, int n_in,
                              void* d_out, int out_size, void* d_ws, size_t ws_size,
                              hipStream_t stream) {
    const int* label = (const int*)d_in[0];
    const float* src = (const float*)d_in[1];
    const float* tgt = (const float*)d_in[2];

    char* ws = (char*)d_ws;
    float* divr  = (float*)(ws + OFF_DIV);
    double* asum = (double*)(ws + OFF_ASUM);
    int* acnt    = (int*)(ws + OFF_ACNT);

    k_main <<<NB, 256, 0, stream>>>(label, src, tgt, divr, asum, acnt);
    k_final<<<1, 320, 0, stream>>>(divr, asum, acnt, (float*)d_out);
}